// Round 13
// baseline (134.603 us; speedup 1.0000x reference)
//
#include <hip/hip_runtime.h>
#include <math.h>

// ---------------------------------------------------------------------------
// Scattering (J=2,L=8,N=32) + GroupNorm(27) + Linear(15552->10), round 13.
// Occupancy-by-decomposition: split at the u0f boundary (r12 was grid-capped
// at 1.875 waves/SIMD; the rounds kernel now gets 3.4):
//   k_u0f    (1536 x 64, LDS 16.9KB): xf inline, u0 plane pipeline (64-lane
//            split-radix passes), s1a (+s0,xf_g if t1==0), u0f -> ws.
//   k_rounds (3456 x 64, LDS 18.2KB): ONE 4-plane 16x16 modulus round;
//            src = xf_g (j1, ch9+) or u0f_g (o2, ch17+).
//   k_gnlin  (64 x 1024): GroupNorm + GEMV(float4).
// ---------------------------------------------------------------------------

constexpr float C32T[32] = {
  1.0000000000f, 0.9807852804f, 0.9238795325f, 0.8314696123f,
  0.7071067812f, 0.5555702330f, 0.3826834324f, 0.1950903220f,
  0.0000000000f,-0.1950903220f,-0.3826834324f,-0.5555702330f,
 -0.7071067812f,-0.8314696123f,-0.9238795325f,-0.9807852804f,
 -1.0000000000f,-0.9807852804f,-0.9238795325f,-0.8314696123f,
 -0.7071067812f,-0.5555702330f,-0.3826834324f,-0.1950903220f,
  0.0000000000f, 0.1950903220f, 0.3826834324f, 0.5555702330f,
  0.7071067812f, 0.8314696123f, 0.9238795325f, 0.9807852804f };
constexpr float S32T[32] = {
  0.0000000000f, 0.1950903220f, 0.3826834324f, 0.5555702330f,
  0.7071067812f, 0.8314696123f, 0.9238795325f, 0.9807852804f,
  1.0000000000f, 0.9807852804f, 0.9238795325f, 0.8314696123f,
  0.7071067812f, 0.5555702330f, 0.3826834324f, 0.1950903220f,
  0.0000000000f,-0.1950903220f,-0.3826834324f,-0.5555702330f,
 -0.7071067812f,-0.8314696123f,-0.9238795325f,-0.9807852804f,
 -1.0000000000f,-0.9807852804f,-0.9238795325f,-0.8314696123f,
 -0.7071067812f,-0.5555702330f,-0.3826834324f,-0.1950903220f };

template<int N>
__device__ __forceinline__ void fftN(float2 (&a)[N], float sgn) {
  constexpr int LOG = (N == 32) ? 5 : ((N == 16) ? 4 : 3);
  #pragma unroll
  for (int i = 0; i < N; ++i) {
    int j = 0;
    #pragma unroll
    for (int bn = 0; bn < LOG; ++bn) j |= ((i >> bn) & 1) << (LOG - 1 - bn);
    if (j > i) { float2 t = a[i]; a[i] = a[j]; a[j] = t; }
  }
  #pragma unroll
  for (int s = 1; s <= LOG; ++s) {
    const int half  = 1 << (s - 1);
    const int tstep = 32 >> s;
    #pragma unroll
    for (int i = 0; i < N; i += (1 << s)) {
      #pragma unroll
      for (int k = 0; k < half; ++k) {
        const int ti = k * tstep;            // compile-time
        const float2 u = a[i + k];
        const float2 v = a[i + k + half];
        float tr, tq;
        if (ti == 0)      { tr = v.x;        tq = v.y; }         // w = 1
        else if (ti == 8) { tr = -sgn * v.y; tq = sgn * v.x; }   // w = i*sgn
        else {
          const float wr = C32T[ti];
          const float wi = sgn * S32T[ti];
          tr = v.x * wr - v.y * wi;
          tq = v.x * wi + v.y * wr;
        }
        a[i + k]        = make_float2(u.x + tr, u.y + tq);
        a[i + k + half] = make_float2(u.x - tr, u.y - tq);
      }
    }
  }
}

// 16-point-per-lane LDS pass (fft16 planes).
template<int N>
__device__ __forceinline__ void passN(float* re, float* im, int off, int st,
                                      float sgn, int md, float scale) {
  float2 a[N];
  #pragma unroll
  for (int i = 0; i < N; ++i) a[i] = make_float2(re[off + i * st], im[off + i * st]);
  #pragma unroll 1
  for (int rep = 0; rep <= md; ++rep) {
    fftN<N>(a, rep ? -1.0f : sgn);
    if (rep == 0 && md) {
      #pragma unroll
      for (int i = 0; i < N; ++i) {
        const float m = sqrtf(a[i].x * a[i].x + a[i].y * a[i].y) * scale;
        a[i] = make_float2(m, 0.0f);
      }
    }
  }
  #pragma unroll
  for (int i = 0; i < N; ++i) { re[off + i * st] = a[i].x; im[off + i * st] = a[i].y; }
}

// 64-lane 32-point pass: lane pair (q=tid>>1, h=tid&1) owns row/col q.
// DIT: load z[2i+h], FFT16(sgn), shfl_xor(1) combine -> lane0 X[0:16],
// lane1 X[16:32]. md=0: store block layout. md=1: modulus, DIF forward,
// store interleaved. (Verified r12.)
__device__ __forceinline__ void pass32p(float* re, float* im, int off, int st,
                                        float sgn, int md, float scale, int h) {
  float2 a[16];
  #pragma unroll
  for (int i = 0; i < 16; ++i) {
    const int idx = off + (2 * i + h) * st;
    a[i] = make_float2(re[idx], im[idx]);
  }
  fftN<16>(a, sgn);
  #pragma unroll
  for (int k = 0; k < 16; ++k) {
    const float wr = h ? C32T[k] : 1.0f;
    const float wi = h ? sgn * S32T[k] : 0.0f;
    const float tr = a[k].x * wr - a[k].y * wi;
    const float tq = a[k].x * wi + a[k].y * wr;
    const float pr = __shfl_xor(tr, 1, 64);
    const float pq = __shfl_xor(tq, 1, 64);
    a[k].x = h ? (pr - tr) : (tr + pr);
    a[k].y = h ? (pq - tq) : (tq + pq);
  }
  if (md) {
    #pragma unroll
    for (int i = 0; i < 16; ++i) {
      const float m = sqrtf(a[i].x * a[i].x + a[i].y * a[i].y) * scale;
      a[i] = make_float2(m, 0.0f);
    }
    #pragma unroll
    for (int k = 0; k < 16; ++k) {
      const float pr = __shfl_xor(a[k].x, 1, 64);
      const float pq = __shfl_xor(a[k].y, 1, 64);
      if (h == 0) { a[k].x += pr; a[k].y += pq; }
      else {
        const float dr = pr - a[k].x, dq = pq - a[k].y;
        const float wr = C32T[k], wi = -S32T[k];
        a[k].x = dr * wr - dq * wi;
        a[k].y = dr * wi + dq * wr;
      }
    }
    fftN<16>(a, -1.0f);
    #pragma unroll
    for (int i = 0; i < 16; ++i) {
      const int idx = off + (2 * i + h) * st;
      re[idx] = a[i].x; im[idx] = a[i].y;
    }
  } else {
    #pragma unroll
    for (int i = 0; i < 16; ++i) {
      const int idx = off + (i + 16 * h) * st;
      re[idx] = a[i].x; im[idx] = a[i].y;
    }
  }
}

// in-register 8x8 inverse FFT2 via shuffle (verified r11/r12)
__device__ __forceinline__ void bfly(float& re, float& im, int m, int n) {
  const float pre = __shfl_xor(re, m, 64);
  const float pim = __shfl_xor(im, m, 64);
  float nr, ni;
  if ((threadIdx.x & m) == 0) { nr = re + pre; ni = im + pim; }
  else {
    const float dr = pre - re, di = pim - im;
    const float h = 0.70710678118654752f;
    const float wr = (n == 0) ? 1.f : ((n == 1) ? h : ((n == 2) ? 0.f : -h));
    const float wi = (n == 0) ? 0.f : ((n == 2) ? 1.f : h);
    nr = dr * wr - di * wi;
    ni = dr * wi + di * wr;
  }
  re = nr; im = ni;
}

__device__ __forceinline__ float ifft8x8_sh(float zr, float zi) {
  const int l = threadIdx.x;
  bfly(zr, zi, 4, l & 3);
  bfly(zr, zi, 2, (l & 1) << 1);
  bfly(zr, zi, 1, 0);
  bfly(zr, zi, 32, (l >> 3) & 3);
  bfly(zr, zi, 16, ((l >> 3) & 1) << 1);
  bfly(zr, zi, 8, 0);
  return zr;
}

__device__ __forceinline__ int rev3(int v) {
  return ((v & 1) << 2) | (v & 2) | ((v >> 2) & 1);
}

// ---------------------------------------------------------------------------
// k_u0f: grid 1536, block 64. LDS = 4*1056*4 = 16896 B (no buffer unions).
// ---------------------------------------------------------------------------
__global__ __launch_bounds__(64) void k_u0f(
    const float* __restrict__ x, const float* __restrict__ psi0,
    const float* __restrict__ phi, float2* __restrict__ xf_g,
    float2* __restrict__ u0f_g, float* __restrict__ feat)
{
  __shared__ float XCr[1056], XCi[1056];  // xf 32x33
  __shared__ float Ar[1056],  Ai[1056];   // u0f plane 32x33
  const int tid = threadIdx.x;
  const int blk = blockIdx.x;
  const int bc = blk >> 3, t1 = blk & 7;
  const int q2 = tid >> 1, h2 = tid & 1;
  const int ur8 = (tid >> 3) & 7, vc8 = tid & 7;
  const int oidx = rev3(ur8) * 8 + rev3(vc8);

  for (int e = tid; e < 1024; e += 64) {
    XCr[(e >> 5) * 33 + (e & 31)] = x[bc * 1024 + e];
    XCi[(e >> 5) * 33 + (e & 31)] = 0.0f;
  }
  __syncthreads();
  #pragma unroll 1
  for (int p = 0; p < 2; ++p) {
    const int so = (p == 1) ? 1 : 33, st = 34 - so;
    pass32p(XCr, XCi, q2 * so, st, -1.0f, 0, 0.0f, h2);
    __syncthreads();
  }
  // A = xf * psi0[t1]
  for (int e = tid; e < 1024; e += 64) {
    const float ps = psi0[t1 * 1024 + e];
    const int o = (e >> 5) * 33 + (e & 31);
    Ar[o] = XCr[o] * ps;
    Ai[o] = XCi[o] * ps;
  }
  __syncthreads();
  #pragma unroll 1
  for (int pp = 0; pp < 3; ++pp) {
    const int so = (pp == 1) ? 1 : 33, st = 34 - so;
    const float sg = (pp == 2) ? -1.0f : 1.0f;
    const int md = (pp == 1) ? 1 : 0;
    pass32p(Ar, Ai, q2 * so, st, sg, md, 1.0f / 1024.0f, h2);
    __syncthreads();
  }
  // u0f -> ws (coalesced float2)
  for (int e = tid; e < 1024; e += 64) {
    const int o = (e >> 5) * 33 + (e & 31);
    u0f_g[((size_t)bc * 8 + t1) * 1024 + e] = make_float2(Ar[o], Ai[o]);
  }
  // t1==0: xf -> ws (for k_rounds' j1 blocks)
  if (t1 == 0) {
    for (int e = tid; e < 1024; e += 64) {
      const int o = (e >> 5) * 33 + (e & 31);
      xf_g[(size_t)bc * 1024 + e] = make_float2(XCr[o], XCi[o]);
    }
  }
  // s1a (from A, ch 1+t1) + s0 (from XC, ch 0, t1==0 only)
  {
    const int nsp = (t1 == 0) ? 2 : 1;
    #pragma unroll 1
    for (int p = 0; p < nsp; ++p) {
      const float* vr_ = (p == 1) ? XCr : Ar;
      const float* vi_ = (p == 1) ? XCi : Ai;
      float zr = 0.f, zi = 0.f;
      #pragma unroll
      for (int i2 = 0; i2 < 4; ++i2)
        #pragma unroll
        for (int j2 = 0; j2 < 4; ++j2) {
          const int r = ur8 + 8 * i2, c = vc8 + 8 * j2;
          const float ph = phi[r * 32 + c];
          zr += vr_[r * 33 + c] * ph;
          zi += vi_[r * 33 + c] * ph;
        }
      zr *= 0.0625f; zi *= 0.0625f;
      const float re = ifft8x8_sh(zr, zi);
      const int ch = (p == 1) ? 0 : (1 + t1);
      feat[((size_t)bc * 81 + ch) * 64 + oidx] = re * (1.0f / 64.0f);
    }
  }
}

// ---------------------------------------------------------------------------
// k_rounds: grid 3456, block 64. LDS = (1056*2 + 1088*2 + 256)*4 = 18176 B.
// blk: t2b=(blk&1)*4; sp=blk>>1. sp<192: j1 (src xf_g, ch 9+t2b);
// else: o2 (src u0f_g[bc,t1], ch 17+t1*8+t2b).
// ---------------------------------------------------------------------------
__global__ __launch_bounds__(64) void k_rounds(
    const float2* __restrict__ xf_g, const float2* __restrict__ u0f_g,
    const float* __restrict__ psi1, const float* __restrict__ phi,
    float* __restrict__ feat)
{
  __shared__ float Ur[1056], Ui[1056];   // src 32x33
  __shared__ float Cr[1088], Ci[1088];   // 4 x 16x17
  __shared__ float P1[256];              // 16x16
  const int tid = threadIdx.x;
  const int blk = blockIdx.x;
  const int t2b = (blk & 1) * 4;
  const int sp = blk >> 1;
  const float2* src;
  int bc, chb;
  if (sp < 192) { bc = sp; src = xf_g + (size_t)sp * 1024; chb = 9 + t2b; }
  else {
    const int s2 = sp - 192;
    bc = s2 >> 3;
    const int t1 = s2 & 7;
    src = u0f_g + ((size_t)bc * 8 + t1) * 1024;
    chb = 17 + t1 * 8 + t2b;
  }
  const int ur8 = (tid >> 3) & 7, vc8 = tid & 7;
  const int oidx = rev3(ur8) * 8 + rev3(vc8);

  for (int e = tid; e < 1024; e += 64) {
    const float2 v = src[e];
    Ur[(e >> 5) * 33 + (e & 31)] = v.x;
    Ui[(e >> 5) * 33 + (e & 31)] = v.y;
  }
  for (int e = tid; e < 256; e += 64) {
    const int u = e >> 4, v = e & 15;
    P1[u * 16 + v] = 0.25f * (phi[u * 32 + v] + phi[u * 32 + v + 16] +
                              phi[(u + 16) * 32 + v] + phi[(u + 16) * 32 + v + 16]);
  }
  __syncthreads();
  // mult + 2x2 fold -> C
  #pragma unroll 4
  for (int e = tid; e < 1024; e += 64) {
    const int q = e >> 8, u = (e >> 4) & 15, v = e & 15;
    const int t2 = t2b + q;
    float sr = 0.f, si = 0.f;
    #pragma unroll
    for (int i2 = 0; i2 < 2; ++i2)
      #pragma unroll
      for (int j2 = 0; j2 < 2; ++j2) {
        const int r = u + 16 * i2, c = v + 16 * j2;
        const float ps = psi1[t2 * 1024 + r * 32 + c];
        sr += Ur[r * 33 + c] * ps;
        si += Ui[r * 33 + c] * ps;
      }
    Cr[q * 272 + u * 17 + v] = 0.25f * sr;
    Ci[q * 272 + u * 17 + v] = 0.25f * si;
  }
  __syncthreads();
  // 3 fft16 passes (p=1 fused modulus); 4 planes x 16 lanes
  #pragma unroll 1
  for (int pp = 0; pp < 3; ++pp) {
    const int q = tid >> 4, it = tid & 15;
    const int so = (pp == 1) ? 1 : 17, st = 18 - so;
    const float sg = (pp == 2) ? -1.0f : 1.0f;
    const int md = (pp == 1) ? 1 : 0;
    passN<16>(Cr + q * 272, Ci + q * 272, it * so, st, sg, md, 1.0f / 256.0f);
    __syncthreads();
  }
  // low-pass fold + shuffle ifft2 per plane -> feat
  #pragma unroll 1
  for (int q = 0; q < 4; ++q) {
    float zr = 0.f, zi = 0.f;
    #pragma unroll
    for (int i2 = 0; i2 < 2; ++i2)
      #pragma unroll
      for (int j2 = 0; j2 < 2; ++j2) {
        const int r = ur8 + 8 * i2, c = vc8 + 8 * j2;
        const float ph = P1[r * 16 + c];
        zr += Cr[q * 272 + r * 17 + c] * ph;
        zi += Ci[q * 272 + r * 17 + c] * ph;
      }
    zr *= 0.25f; zi *= 0.25f;
    const float re = ifft8x8_sh(zr, zi);
    feat[((size_t)bc * 81 + chb + q) * 64 + oidx] = re * (1.0f / 64.0f);
  }
}

// ---------------------------------------------------------------------------
// k_gnlin: GroupNorm(27) + Linear(15552->10). grid 64, block 1024.
// ---------------------------------------------------------------------------
__global__ __launch_bounds__(1024) void k_gnlin(
    const float* __restrict__ feat, const float* __restrict__ gamma,
    const float* __restrict__ beta, const float* __restrict__ W,
    const float* __restrict__ bias, float* __restrict__ out)
{
  __shared__ __align__(16) float F[15552];
  __shared__ float gmu[27], grs[27];
  __shared__ float red[160];
  const int tid = threadIdx.x, b = blockIdx.x;
  const float4* fp4 = reinterpret_cast<const float4*>(feat + (size_t)b * 15552);
  float4* F4 = reinterpret_cast<float4*>(F);
  for (int i4 = tid; i4 < 3888; i4 += 1024) F4[i4] = fp4[i4];
  __syncthreads();
  if (tid < 432) {
    const int g = tid >> 4, l = tid & 15;
    float s = 0.f, ss = 0.f;
    for (int e = l; e < 576; e += 16) { const float v = F[g * 576 + e]; s += v; ss += v * v; }
    #pragma unroll
    for (int off = 1; off < 16; off <<= 1) { s += __shfl_xor(s, off, 16); ss += __shfl_xor(ss, off, 16); }
    if (l == 0) {
      const float mu = s * (1.0f / 576.0f);
      gmu[g] = mu;
      grs[g] = rsqrtf(ss * (1.0f / 576.0f) - mu * mu + 1e-5f);
    }
  }
  __syncthreads();
  for (int e = tid; e < 15552; e += 1024) {
    const int ch = e >> 6, g = ch / 9;
    F[e] = (F[e] - gmu[g]) * grs[g] * gamma[ch] + beta[ch];
  }
  __syncthreads();
  float acc[10];
  #pragma unroll
  for (int k = 0; k < 10; ++k) acc[k] = 0.f;
  const float4* W4 = reinterpret_cast<const float4*>(W);
  for (int i4 = tid; i4 < 3888; i4 += 1024) {
    const float4 f = F4[i4];
    #pragma unroll
    for (int k = 0; k < 10; ++k) {
      const float4 w = W4[(size_t)k * 3888 + i4];
      acc[k] = fmaf(f.x, w.x, fmaf(f.y, w.y, fmaf(f.z, w.z, fmaf(f.w, w.w, acc[k]))));
    }
  }
  #pragma unroll
  for (int k = 0; k < 10; ++k) {
    float v = acc[k];
    #pragma unroll
    for (int off = 32; off > 0; off >>= 1) v += __shfl_down(v, off);
    if ((tid & 63) == 0) red[(tid >> 6) * 10 + k] = v;
  }
  __syncthreads();
  if (tid < 10) {
    float s = bias[tid];
    #pragma unroll
    for (int w = 0; w < 16; ++w) s += red[w * 10 + tid];
    out[b * 10 + tid] = s;
  }
}

// ---------------------------------------------------------------------------
extern "C" void kernel_launch(void* const* d_in, const int* in_sizes, int n_in,
                              void* d_out, int out_size, void* d_ws, size_t ws_size,
                              hipStream_t stream) {
  (void)in_sizes; (void)n_in; (void)out_size; (void)ws_size;
  const float* x     = (const float*)d_in[0];
  const float* psi0  = (const float*)d_in[1];
  const float* psi1  = (const float*)d_in[2];
  const float* phi   = (const float*)d_in[3];
  const float* gamma = (const float*)d_in[4];
  const float* beta  = (const float*)d_in[5];
  const float* W     = (const float*)d_in[6];
  const float* bias  = (const float*)d_in[7];
  float* out = (float*)d_out;

  float2* xf_g  = (float2*)d_ws;                                // 1.5 MB
  float2* u0f_g = xf_g + (size_t)192 * 1024;                    // 12.6 MB
  float*  feat  = (float*)(u0f_g + (size_t)192 * 8 * 1024);     // 4 MB

  hipLaunchKernelGGL(k_u0f,    dim3(1536), dim3(64),   0, stream, x, psi0, phi, xf_g, u0f_g, feat);
  hipLaunchKernelGGL(k_rounds, dim3(3456), dim3(64),   0, stream, xf_g, u0f_g, psi1, phi, feat);
  hipLaunchKernelGGL(k_gnlin,  dim3(64),   dim3(1024), 0, stream, feat, gamma, beta, W, bias, out);
}

// Round 14
// 114.226 us; speedup vs baseline: 1.1784x; 1.1784x over previous
//
#include <hip/hip_runtime.h>
#include <math.h>

// ---------------------------------------------------------------------------
// Scattering (J=2,L=8,N=32) + GroupNorm(27) + Linear(15552->10), round 14.
// = round 12 (best, 119.6us) with INTERLEAVED float2 LDS everywhere:
// one ds_read_b64/ds_write_b64 per complex element instead of two b32 ops.
// Theory: k_scat's LDS pipe carries ~1600 ops/lane/chain (~20us/CU of the
// 41us) — halving the op count attacks the dominant non-VALU issue stream.
// Structure, math, indexing identical to r12 (which passed absmax=0).
//   k_scat (1920 x 64, LDS 18432B): blocks 0..1535 (bc,t1) u0f + 2 o2 rounds;
//                                   blocks 1536..1919 (bc,half) j1 round.
//   k_gnlin (64 x 1024): GroupNorm + GEMV(float4).
// ---------------------------------------------------------------------------

constexpr float C32T[32] = {
  1.0000000000f, 0.9807852804f, 0.9238795325f, 0.8314696123f,
  0.7071067812f, 0.5555702330f, 0.3826834324f, 0.1950903220f,
  0.0000000000f,-0.1950903220f,-0.3826834324f,-0.5555702330f,
 -0.7071067812f,-0.8314696123f,-0.9238795325f,-0.9807852804f,
 -1.0000000000f,-0.9807852804f,-0.9238795325f,-0.8314696123f,
 -0.7071067812f,-0.5555702330f,-0.3826834324f,-0.1950903220f,
  0.0000000000f, 0.1950903220f, 0.3826834324f, 0.5555702330f,
  0.7071067812f, 0.8314696123f, 0.9238795325f, 0.9807852804f };
constexpr float S32T[32] = {
  0.0000000000f, 0.1950903220f, 0.3826834324f, 0.5555702330f,
  0.7071067812f, 0.8314696123f, 0.9238795325f, 0.9807852804f,
  1.0000000000f, 0.9807852804f, 0.9238795325f, 0.8314696123f,
  0.7071067812f, 0.5555702330f, 0.3826834324f, 0.1950903220f,
  0.0000000000f,-0.1950903220f,-0.3826834324f,-0.5555702330f,
 -0.7071067812f,-0.8314696123f,-0.9238795325f,-0.9807852804f,
 -1.0000000000f,-0.9807852804f,-0.9238795325f,-0.8314696123f,
 -0.7071067812f,-0.5555702330f,-0.3826834324f,-0.1950903220f };

template<int N>
__device__ __forceinline__ void fftN(float2 (&a)[N], float sgn) {
  constexpr int LOG = (N == 32) ? 5 : ((N == 16) ? 4 : 3);
  #pragma unroll
  for (int i = 0; i < N; ++i) {
    int j = 0;
    #pragma unroll
    for (int bn = 0; bn < LOG; ++bn) j |= ((i >> bn) & 1) << (LOG - 1 - bn);
    if (j > i) { float2 t = a[i]; a[i] = a[j]; a[j] = t; }
  }
  #pragma unroll
  for (int s = 1; s <= LOG; ++s) {
    const int half  = 1 << (s - 1);
    const int tstep = 32 >> s;
    #pragma unroll
    for (int i = 0; i < N; i += (1 << s)) {
      #pragma unroll
      for (int k = 0; k < half; ++k) {
        const int ti = k * tstep;            // compile-time
        const float2 u = a[i + k];
        const float2 v = a[i + k + half];
        float tr, tq;
        if (ti == 0)      { tr = v.x;        tq = v.y; }         // w = 1
        else if (ti == 8) { tr = -sgn * v.y; tq = sgn * v.x; }   // w = i*sgn
        else {
          const float wr = C32T[ti];
          const float wi = sgn * S32T[ti];
          tr = v.x * wr - v.y * wi;
          tq = v.x * wi + v.y * wr;
        }
        a[i + k]        = make_float2(u.x + tr, u.y + tq);
        a[i + k + half] = make_float2(u.x - tr, u.y - tq);
      }
    }
  }
}

// 16-point-per-lane LDS pass on interleaved float2 buffer.
template<int N>
__device__ __forceinline__ void passN(float2* buf, int off, int st,
                                      float sgn, int md, float scale) {
  float2 a[N];
  #pragma unroll
  for (int i = 0; i < N; ++i) a[i] = buf[off + i * st];
  #pragma unroll 1
  for (int rep = 0; rep <= md; ++rep) {
    fftN<N>(a, rep ? -1.0f : sgn);
    if (rep == 0 && md) {
      #pragma unroll
      for (int i = 0; i < N; ++i) {
        const float m = sqrtf(a[i].x * a[i].x + a[i].y * a[i].y) * scale;
        a[i] = make_float2(m, 0.0f);
      }
    }
  }
  #pragma unroll
  for (int i = 0; i < N; ++i) buf[off + i * st] = a[i];
}

// 64-lane 32-point pass on interleaved float2 buffer (lane pair q=tid>>1,
// h=tid&1 owns row/col q). Verified logic from r12, loads/stores now b64.
__device__ __forceinline__ void pass32p(float2* buf, int off, int st,
                                        float sgn, int md, float scale, int h) {
  float2 a[16];
  #pragma unroll
  for (int i = 0; i < 16; ++i) a[i] = buf[off + (2 * i + h) * st];
  fftN<16>(a, sgn);
  #pragma unroll
  for (int k = 0; k < 16; ++k) {
    const float wr = h ? C32T[k] : 1.0f;
    const float wi = h ? sgn * S32T[k] : 0.0f;
    const float tr = a[k].x * wr - a[k].y * wi;
    const float tq = a[k].x * wi + a[k].y * wr;
    const float pr = __shfl_xor(tr, 1, 64);
    const float pq = __shfl_xor(tq, 1, 64);
    a[k].x = h ? (pr - tr) : (tr + pr);
    a[k].y = h ? (pq - tq) : (tq + pq);
  }
  if (md) {
    #pragma unroll
    for (int i = 0; i < 16; ++i) {
      const float m = sqrtf(a[i].x * a[i].x + a[i].y * a[i].y) * scale;
      a[i] = make_float2(m, 0.0f);
    }
    #pragma unroll
    for (int k = 0; k < 16; ++k) {
      const float pr = __shfl_xor(a[k].x, 1, 64);
      const float pq = __shfl_xor(a[k].y, 1, 64);
      if (h == 0) { a[k].x += pr; a[k].y += pq; }
      else {
        const float dr = pr - a[k].x, dq = pq - a[k].y;
        const float wr = C32T[k], wi = -S32T[k];
        a[k].x = dr * wr - dq * wi;
        a[k].y = dr * wi + dq * wr;
      }
    }
    fftN<16>(a, -1.0f);
    #pragma unroll
    for (int i = 0; i < 16; ++i) buf[off + (2 * i + h) * st] = a[i];
  } else {
    #pragma unroll
    for (int i = 0; i < 16; ++i) buf[off + (i + 16 * h) * st] = a[i];
  }
}

// in-register 8x8 inverse FFT2 via shuffle (verified r11/r12)
__device__ __forceinline__ void bfly(float& re, float& im, int m, int n) {
  const float pre = __shfl_xor(re, m, 64);
  const float pim = __shfl_xor(im, m, 64);
  float nr, ni;
  if ((threadIdx.x & m) == 0) { nr = re + pre; ni = im + pim; }
  else {
    const float dr = pre - re, di = pim - im;
    const float h = 0.70710678118654752f;
    const float wr = (n == 0) ? 1.f : ((n == 1) ? h : ((n == 2) ? 0.f : -h));
    const float wi = (n == 0) ? 0.f : ((n == 2) ? 1.f : h);
    nr = dr * wr - di * wi;
    ni = dr * wi + di * wr;
  }
  re = nr; im = ni;
}

__device__ __forceinline__ float ifft8x8_sh(float zr, float zi) {
  const int l = threadIdx.x;
  bfly(zr, zi, 4, l & 3);
  bfly(zr, zi, 2, (l & 1) << 1);
  bfly(zr, zi, 1, 0);
  bfly(zr, zi, 32, (l >> 3) & 3);
  bfly(zr, zi, 16, ((l >> 3) & 1) << 1);
  bfly(zr, zi, 8, 0);
  return zr;
}

__device__ __forceinline__ int rev3(int v) {
  return ((v & 1) << 2) | (v & 2) | ((v >> 2) & 1);
}

// ---------------------------------------------------------------------------
// k_scat: grid 1920, block 64. LDS = 1088*8(XC2) + 1088*8(A2) + 256*4(P1)
//       = 18432 B. XC2: xf 32x33 then C 4x16x17 (u0 blocks);
//                  A2 : u0f plane (u0) / C (j1). Both sized 1088 (C max 1087).
// ---------------------------------------------------------------------------
__global__ __launch_bounds__(64) void k_scat(
    const float* __restrict__ x, const float* __restrict__ psi0,
    const float* __restrict__ psi1, const float* __restrict__ phi,
    float* __restrict__ feat)
{
  __shared__ float2 XC2[1088];
  __shared__ float2 A2[1088];
  __shared__ float  P1[256];
  const int tid = threadIdx.x;
  const int blk = blockIdx.x;
  const bool is_u0 = blk < 1536;
  const int bc = is_u0 ? (blk >> 3) : ((blk - 1536) >> 1);
  const int t1 = is_u0 ? (blk & 7) : 0;
  const int q2 = tid >> 1, h2 = tid & 1;
  const int ur8 = (tid >> 3) & 7, vc8 = tid & 7;
  const int oidx = rev3(ur8) * 8 + rev3(vc8);

  // ---- stage x, phi1; xf = fft2(x) ----
  for (int e = tid; e < 1024; e += 64) {
    XC2[(e >> 5) * 33 + (e & 31)] = make_float2(x[bc * 1024 + e], 0.0f);
  }
  for (int e = tid; e < 256; e += 64) {
    const int u = e >> 4, v = e & 15;
    P1[u * 16 + v] = 0.25f * (phi[u * 32 + v] + phi[u * 32 + v + 16] +
                              phi[(u + 16) * 32 + v] + phi[(u + 16) * 32 + v + 16]);
  }
  __syncthreads();
  #pragma unroll 1
  for (int p = 0; p < 2; ++p) {
    const int so = (p == 1) ? 1 : 33, st = 34 - so;
    pass32p(XC2, q2 * so, st, -1.0f, 0, 0.0f, h2);
    __syncthreads();
  }

  if (is_u0) {
    // ---- u0 plane t1: A = xf*psi0[t1]; 3 passes (p=1 fused modulus) ----
    for (int e = tid; e < 1024; e += 64) {
      const float ps = psi0[t1 * 1024 + e];
      const int o = (e >> 5) * 33 + (e & 31);
      const float2 v = XC2[o];
      A2[o] = make_float2(v.x * ps, v.y * ps);
    }
    __syncthreads();
    #pragma unroll 1
    for (int pp = 0; pp < 3; ++pp) {
      const int so = (pp == 1) ? 1 : 33, st = 34 - so;
      const float sg = (pp == 2) ? -1.0f : 1.0f;
      const int md = (pp == 1) ? 1 : 0;
      pass32p(A2, q2 * so, st, sg, md, 1.0f / 1024.0f, h2);
      __syncthreads();
    }
    // ---- s1a (from A2) + s0 (from XC2, t1==0 only): fold + shuffle ifft2 ----
    {
      const int nsp = (t1 == 0) ? 2 : 1;
      #pragma unroll 1
      for (int p = 0; p < nsp; ++p) {
        const float2* vb = (p == 1) ? XC2 : A2;
        float zr = 0.f, zi = 0.f;
        #pragma unroll
        for (int i2 = 0; i2 < 4; ++i2)
          #pragma unroll
          for (int j2 = 0; j2 < 4; ++j2) {
            const int r = ur8 + 8 * i2, c = vc8 + 8 * j2;
            const float ph = phi[r * 32 + c];
            const float2 v = vb[r * 33 + c];
            zr += v.x * ph;
            zi += v.y * ph;
          }
        zr *= 0.0625f; zi *= 0.0625f;
        const float re = ifft8x8_sh(zr, zi);
        const int ch = (p == 1) ? 0 : (1 + t1);
        feat[((size_t)bc * 81 + ch) * 64 + oidx] = re * (1.0f / 64.0f);
      }
    }
    __syncthreads();   // XC2 (=C-space) about to be overwritten by o2 rounds
  }

  // ---- 16x16 modulus rounds: u0 blocks 2 rounds (o2), j1 blocks 1 round ----
  // u0: src = A2 (u0f), C = XC2.  j1: src = XC2 (xf), C = A2.
  {
    const float2* ub = is_u0 ? A2 : XC2;
    float2* Cb = is_u0 ? XC2 : A2;
    const int nr = is_u0 ? 2 : 1;
    const int t2b0 = is_u0 ? 0 : ((blk - 1536) & 1) * 4;
    #pragma unroll 1
    for (int rd = 0; rd < nr; ++rd) {
      const int t2b = is_u0 ? rd * 4 : t2b0;
      const int chb = is_u0 ? (17 + t1 * 8 + t2b) : (9 + t2b0);
      // mult + 2x2 fold
      #pragma unroll 4
      for (int e = tid; e < 1024; e += 64) {
        const int q = e >> 8, u = (e >> 4) & 15, v = e & 15;
        const int t2 = t2b + q;
        float sr = 0.f, si = 0.f;
        #pragma unroll
        for (int i2 = 0; i2 < 2; ++i2)
          #pragma unroll
          for (int j2 = 0; j2 < 2; ++j2) {
            const int r = u + 16 * i2, c = v + 16 * j2;
            const float ps = psi1[t2 * 1024 + r * 32 + c];
            const float2 uv = ub[r * 33 + c];
            sr += uv.x * ps;
            si += uv.y * ps;
          }
        Cb[q * 272 + u * 17 + v] = make_float2(0.25f * sr, 0.25f * si);
      }
      __syncthreads();
      // 3 fft16 passes (p=1 fused modulus); 4 planes x 16 lanes
      #pragma unroll 1
      for (int pp = 0; pp < 3; ++pp) {
        const int q = tid >> 4, it = tid & 15;
        const int so = (pp == 1) ? 1 : 17, st = 18 - so;
        const float sg = (pp == 2) ? -1.0f : 1.0f;
        const int md = (pp == 1) ? 1 : 0;
        passN<16>(Cb + q * 272, it * so, st, sg, md, 1.0f / 256.0f);
        __syncthreads();
      }
      // low-pass fold + shuffle ifft2 per plane -> feat
      #pragma unroll 1
      for (int q = 0; q < 4; ++q) {
        float zr = 0.f, zi = 0.f;
        #pragma unroll
        for (int i2 = 0; i2 < 2; ++i2)
          #pragma unroll
          for (int j2 = 0; j2 < 2; ++j2) {
            const int r = ur8 + 8 * i2, c = vc8 + 8 * j2;
            const float ph = P1[r * 16 + c];
            const float2 cv = Cb[q * 272 + r * 17 + c];
            zr += cv.x * ph;
            zi += cv.y * ph;
          }
        zr *= 0.25f; zi *= 0.25f;
        const float re = ifft8x8_sh(zr, zi);
        feat[((size_t)bc * 81 + chb + q) * 64 + oidx] = re * (1.0f / 64.0f);
      }
      __syncthreads();   // C reused next round (u0 blocks)
    }
  }
}

// ---------------------------------------------------------------------------
// k_gnlin: GroupNorm(27) + Linear(15552->10). grid 64, block 1024.
// ---------------------------------------------------------------------------
__global__ __launch_bounds__(1024) void k_gnlin(
    const float* __restrict__ feat, const float* __restrict__ gamma,
    const float* __restrict__ beta, const float* __restrict__ W,
    const float* __restrict__ bias, float* __restrict__ out)
{
  __shared__ __align__(16) float F[15552];
  __shared__ float gmu[27], grs[27];
  __shared__ float red[160];
  const int tid = threadIdx.x, b = blockIdx.x;
  const float4* fp4 = reinterpret_cast<const float4*>(feat + (size_t)b * 15552);
  float4* F4 = reinterpret_cast<float4*>(F);
  for (int i4 = tid; i4 < 3888; i4 += 1024) F4[i4] = fp4[i4];
  __syncthreads();
  if (tid < 432) {
    const int g = tid >> 4, l = tid & 15;
    float s = 0.f, ss = 0.f;
    for (int e = l; e < 576; e += 16) { const float v = F[g * 576 + e]; s += v; ss += v * v; }
    #pragma unroll
    for (int off = 1; off < 16; off <<= 1) { s += __shfl_xor(s, off, 16); ss += __shfl_xor(ss, off, 16); }
    if (l == 0) {
      const float mu = s * (1.0f / 576.0f);
      gmu[g] = mu;
      grs[g] = rsqrtf(ss * (1.0f / 576.0f) - mu * mu + 1e-5f);
    }
  }
  __syncthreads();
  for (int e = tid; e < 15552; e += 1024) {
    const int ch = e >> 6, g = ch / 9;
    F[e] = (F[e] - gmu[g]) * grs[g] * gamma[ch] + beta[ch];
  }
  __syncthreads();
  float acc[10];
  #pragma unroll
  for (int k = 0; k < 10; ++k) acc[k] = 0.f;
  const float4* W4 = reinterpret_cast<const float4*>(W);
  for (int i4 = tid; i4 < 3888; i4 += 1024) {
    const float4 f = F4[i4];
    #pragma unroll
    for (int k = 0; k < 10; ++k) {
      const float4 w = W4[(size_t)k * 3888 + i4];
      acc[k] = fmaf(f.x, w.x, fmaf(f.y, w.y, fmaf(f.z, w.z, fmaf(f.w, w.w, acc[k]))));
    }
  }
  #pragma unroll
  for (int k = 0; k < 10; ++k) {
    float v = acc[k];
    #pragma unroll
    for (int off = 32; off > 0; off >>= 1) v += __shfl_down(v, off);
    if ((tid & 63) == 0) red[(tid >> 6) * 10 + k] = v;
  }
  __syncthreads();
  if (tid < 10) {
    float s = bias[tid];
    #pragma unroll
    for (int w = 0; w < 16; ++w) s += red[w * 10 + tid];
    out[b * 10 + tid] = s;
  }
}

// ---------------------------------------------------------------------------
extern "C" void kernel_launch(void* const* d_in, const int* in_sizes, int n_in,
                              void* d_out, int out_size, void* d_ws, size_t ws_size,
                              hipStream_t stream) {
  (void)in_sizes; (void)n_in; (void)out_size; (void)ws_size;
  const float* x     = (const float*)d_in[0];
  const float* psi0  = (const float*)d_in[1];
  const float* psi1  = (const float*)d_in[2];
  const float* phi   = (const float*)d_in[3];
  const float* gamma = (const float*)d_in[4];
  const float* beta  = (const float*)d_in[5];
  const float* W     = (const float*)d_in[6];
  const float* bias  = (const float*)d_in[7];
  float* out = (float*)d_out;

  float* feat = (float*)d_ws;   // 64*15552 f32 = 4 MB

  hipLaunchKernelGGL(k_scat,  dim3(1920), dim3(64),   0, stream, x, psi0, psi1, phi, feat);
  hipLaunchKernelGGL(k_gnlin, dim3(64),   dim3(1024), 0, stream, feat, gamma, beta, W, bias, out);
}